// Round 6
// baseline (984.452 us; speedup 1.0000x reference)
//
#include <hip/hip_runtime.h>
#include <hip/hip_bf16.h>
#include <stdint.h>

#define VOCAB 30000
#define EMBED 256
#define HID   128
#define BB    256
#define TT    512
#define G4    (4*HID)    // 512 gate columns per direction
#define GW    (2*G4)     // 1024 columns in embW (fw | bw)
#define BPB   2          // batches per lstm block

typedef _Float16 f16x8 __attribute__((ext_vector_type(8)));
typedef _Float16 f16x4 __attribute__((ext_vector_type(4)));
typedef float    f32x4 __attribute__((ext_vector_type(4)));

__device__ __forceinline__ float sigm(float x){
  return 1.0f / (1.0f + __expf(-x));
}
__device__ __forceinline__ float fast_tanh(float x){
  float e = __expf(2.0f * x);
  return 1.0f - 2.0f / (e + 1.0f);
}

// ---------------------------------------------------------------------------
// Kernel 1: EW[v][g] = emb[v][:] @ [Wf|Wb][:,g] + bias[g]   via MFMA f16.
// ---------------------------------------------------------------------------
__global__ __launch_bounds__(256, 4) void embw_mfma(
    const float* __restrict__ emb,
    const float* __restrict__ Wf, const float* __restrict__ Wb,
    const float* __restrict__ bf, const float* __restrict__ bb,
    float* __restrict__ EW)
{
  __shared__ _Float16 As[64*EMBED];   // 32 KB
  const int tid = threadIdx.x;
  const int l   = tid & 63;
  const int w   = tid >> 6;
  const int r0  = blockIdx.x * 64;
  const int c0  = blockIdx.y * 64;
  const int nr  = min(64, VOCAB - r0);

  const float4* asrc = (const float4*)(emb + (size_t)r0*EMBED);
  for (int i = tid; i < nr*(EMBED/4); i += 256){
    float4 v = asrc[i];
    const int row = i >> 6;
    const int kc  = (i & 63) * 4;
    const int ks  = kc ^ ((row & 7) << 3);
    _Float16* dst = &As[row*EMBED + ks];
    dst[0]=(_Float16)v.x; dst[1]=(_Float16)v.y;
    dst[2]=(_Float16)v.z; dst[3]=(_Float16)v.w;
  }
  __syncthreads();

  const int cl = w*16 + (l & 15);
  const int cg = c0 + cl;
  const float* Wsrc = (cg < G4) ? (Wf + cg) : (Wb + (cg - G4));
  const int kg = (l >> 4) * 8;

  f32x4 acc[4] = {{0,0,0,0},{0,0,0,0},{0,0,0,0},{0,0,0,0}};

  for (int kk = 0; kk < EMBED/32; ++kk){
    const int kb = kk*32 + kg;
    f16x8 bfrag;
    #pragma unroll
    for (int j = 0; j < 8; ++j)
      bfrag[j] = (_Float16)Wsrc[(size_t)(kb + j)*G4];
    #pragma unroll
    for (int m = 0; m < 4; ++m){
      const int row = m*16 + (l & 15);
      const int ks  = kb ^ ((row & 7) << 3);
      f16x8 afrag = *(const f16x8*)&As[row*EMBED + ks];
      acc[m] = __builtin_amdgcn_mfma_f32_16x16x32_f16(afrag, bfrag, acc[m], 0, 0, 0);
    }
  }

  const float bv = (cg < G4) ? bf[cg] : bb[cg - G4];
  #pragma unroll
  for (int m = 0; m < 4; ++m){
    #pragma unroll
    for (int r = 0; r < 4; ++r){
      const int vrow = r0 + m*16 + (l >> 4)*4 + r;
      if (vrow < VOCAB)
        EW[(size_t)vrow*GW + cg] = acc[m][r] + bv;
    }
  }
}

// ---------------------------------------------------------------------------
// Kernel 2: recurrence, swapped-operand MFMA. One block = 2 batches x 1 dir.
// D[ucol][batch] = U^T(A) x h(B): lane (lr=batch, hi=q) reg r holds
// z[batch][w*16 + hi*4 + r] directly -> no cross-lane redistribution.
// h crosses waves via a 1 KB double-buffered LDS tile (broadcast reads,
// 2-way max aliasing). ONE barrier per step. xw addresses precomputed 2
// steps ahead; loads issue at top-of-step with no dependencies.
// ---------------------------------------------------------------------------
__global__ __launch_bounds__(512, 2) void lstm_swap(
    const int*   __restrict__ tokens,
    const float* __restrict__ EW,
    const float* __restrict__ Ufw, const float* __restrict__ Ubw,
    float* __restrict__ out)
{
  __shared__ _Float16 h_lds[2][2*HID];    // double buffer, 2 batches x 128, 1 KB
  __shared__ int      tok_lds[BPB*TT];    // 4 KB

  const int tid = threadIdx.x;
  const int l   = tid & 63;
  const int w   = tid >> 6;               // wave 0..7
  const int lr  = l & 15;                 // batch col (valid < 2)
  const int hi  = l >> 4;                 // q = k-chunk / ucol quad
  const int dir = blockIdx.x & 1;
  const int b0  = (blockIdx.x >> 1) * BPB;

  if (tid < 2*2*HID) ((_Float16*)h_lds)[tid] = (_Float16)0.f;
  for (int i = tid; i < BPB*TT; i += 512)
    tok_lds[i] = tokens[(b0 + (i >> 9))*TT + (i & 511)];
  __syncthreads();

  // ---- resident U fragments (A-operand): ub[kt][gate], 64 VGPRs ----
  // A[m=ucol_local][k]: lane row = lr -> ucol = w*16+lr ; k = kt*32 + hi*8 + j
  const float* U = dir ? Ubw : Ufw;
  f16x8 ub[4][4];
  #pragma unroll
  for (int kt = 0; kt < 4; ++kt){
    #pragma unroll
    for (int g = 0; g < 4; ++g){
      const int col = g*128 + w*16 + lr;
      f16x8 f;
      #pragma unroll
      for (int j = 0; j < 8; ++j)
        f[j] = (_Float16)U[(size_t)(kt*32 + hi*8 + j)*G4 + col];
      ub[kt][g] = f;
    }
  }

  const bool act = (lr < BPB);            // this lane owns batch lr
  f32x4 xwc[4], xwn[4];
  f32x4 creg = {0,0,0,0}, hfin = {0,0,0,0};
  #pragma unroll
  for (int g = 0; g < 4; ++g){ xwc[g] = (f32x4){0,0,0,0}; }

  // ---- prologue: xw for step 0, address for step 1 ----
  const float* e_next = EW;
  if (act){
    const int t0 = dir ? (TT-1) : 0;
    const float* e0 = EW + (size_t)tok_lds[lr*TT + t0]*GW + dir*G4 + w*16 + hi*4;
    #pragma unroll
    for (int g = 0; g < 4; ++g) xwc[g] = *(const f32x4*)(e0 + g*128);
    const int t1 = dir ? (TT-2) : 1;
    e_next = EW + (size_t)tok_lds[lr*TT + t1]*GW + dir*G4 + w*16 + hi*4;
  }

  for (int s = 0; s < TT; ++s){
    const int t   = dir ? (TT-1-s) : s;
    const int cur = s & 1, nxt = cur ^ 1;

    // 1. issue xw loads for step s+1 (addresses precomputed, zero deps)
    #pragma unroll
    for (int g = 0; g < 4; ++g) xwn[g] = (f32x4){0,0,0,0};
    if (act){
      #pragma unroll
      for (int g = 0; g < 4; ++g) xwn[g] = *(const f32x4*)(e_next + g*128);
    }

    // 2. precompute address for step s+2 (off critical path)
    if (act){
      int sn = s + 2; sn = sn < TT ? sn : TT-1;
      const int t2 = dir ? (TT-1-sn) : sn;
      e_next = EW + (size_t)tok_lds[lr*TT + t2]*GW + dir*G4 + w*16 + hi*4;
    }

    // 3. h B-fragments: col = batch (lanes >=2 replicate batch lr&1)
    f16x8 hb[4];
    {
      const char* hrow = (const char*)h_lds[cur] + (lr & 1)*256;
      #pragma unroll
      for (int kt = 0; kt < 4; ++kt)
        hb[kt] = *(const f16x8*)(hrow + kt*64 + hi*16);
    }

    // 4. MFMA: z = xw + U^T h  (4 independent gate chains)
    f32x4 acc[4];
    #pragma unroll
    for (int g = 0; g < 4; ++g) acc[g] = xwc[g];
    #pragma unroll
    for (int kt = 0; kt < 4; ++kt){
      #pragma unroll
      for (int g = 0; g < 4; ++g)
        acc[g] = __builtin_amdgcn_mfma_f32_16x16x32_f16(ub[kt][g], hb[kt], acc[g], 0, 0, 0);
    }

    // 5. gates: lane holds z[i,f,g,o] for 4 hidden units of its batch
    if (act){
      float hh[4];
      #pragma unroll
      for (int r = 0; r < 4; ++r){
        const float zi = acc[0][r], zf = acc[1][r];
        const float zg = acc[2][r], zo = acc[3][r];
        const float cn = sigm(zf)*creg[r] + sigm(zi)*fast_tanh(zg);
        creg[r] = cn;
        hh[r] = sigm(zo)*fast_tanh(cn);
        hfin[r] = hh[r];
      }
      f16x4 hp = { (_Float16)hh[0], (_Float16)hh[1],
                   (_Float16)hh[2], (_Float16)hh[3] };
      // h index = lr*128 + w*16 + hi*4  (byte: lr*256 + w*32 + hi*8)
      *(f16x4*)((char*)h_lds[nxt] + lr*256 + w*32 + hi*8) = hp;
      f32x4 o = { hh[0], hh[1], hh[2], hh[3] };
      *(f32x4*)(out + ((size_t)(b0+lr)*TT + t)*(2*HID) + (size_t)dir*HID
                    + w*16 + hi*4) = o;
    }

    asm volatile("s_waitcnt lgkmcnt(0)" ::: "memory");
    __builtin_amdgcn_s_barrier();

    #pragma unroll
    for (int g = 0; g < 4; ++g) xwc[g] = xwn[g];
  }

  // ---- final h_T / c_T (float4 per active lane) ----
  if (act){
    const size_t O1  = (size_t)BB*TT*(2*HID);
    const size_t idx = (size_t)(b0+lr)*HID + w*16 + hi*4;
    float* hb_out = out + O1 + (dir ? 2*(size_t)BB*HID : 0);
    float* cb_out = out + O1 + (dir ? 3*(size_t)BB*HID : (size_t)BB*HID);
    *(f32x4*)(hb_out + idx) = hfin;
    *(f32x4*)(cb_out + idx) = creg;
  }
}

extern "C" void kernel_launch(void* const* d_in, const int* in_sizes, int n_in,
                              void* d_out, int out_size, void* d_ws, size_t ws_size,
                              hipStream_t stream)
{
  const int*   tokens = (const int*)  d_in[0];
  const float* emb    = (const float*)d_in[1];
  const float* Wf     = (const float*)d_in[2];
  const float* Ufw    = (const float*)d_in[3];
  const float* bf     = (const float*)d_in[4];
  const float* Wb     = (const float*)d_in[5];
  const float* Ubw    = (const float*)d_in[6];
  const float* bb     = (const float*)d_in[7];
  float* out = (float*)d_out;
  float* EW  = (float*)d_ws;          // 30000 x 1024 f32 = 122.88 MB

  embw_mfma<<<dim3((VOCAB + 63)/64, GW/64), 256, 0, stream>>>(emb, Wf, Wb, bf, bb, EW);
  lstm_swap<<<(BB/BPB)*2, 512, 0, stream>>>(tokens, EW, Ufw, Ubw, out);
}